// Round 6
// baseline (134.511 us; speedup 1.0000x reference)
//
#include <hip/hip_runtime.h>
#include <math.h>

// Tropical (max-plus) matmul: out[b,o] = max_k ( x[b,k] + W[o,k] )
// x: (2048,512) f32, W: (512,512) f32, out: (2048,512) f32.
//
// R5 post-mortem (counters): LDS broadcast return path 384 cyc/CU/kq vs VALU
// 128 -> VALUBusy 33% exactly; pipes serialized (sum ~45us = measured 48.6).
// R6: raise arithmetic per LDS/VMEM instr and software-pipeline explicitly.
//   - lane<->col, C=8 cols/lane (whole 512-col width per wave), R=8 rows/wave:
//     per kq per wave: 8 ds_read_b128 + 8 coalesced dwordx4 + 256 VALU
//     (v_pk_add_f32 + v_max3_f32). Per-CU/kq: VALU 1024 >= VMEM 1024 > LDS 768.
//   - split-K=8 restores parallelism: 512 blocks (2/CU), 8 waves/CU.
//     Partials (32 MB) in ws + 8-way max reduce kernel.
//   - explicit 2-deep register double-buffer prefetch (~580 cyc compute per kq
//     covers L2 latency); ~200 VGPRs, still 2 waves/SIMD.
// Fixed ~54 us of dur_us is the harness ws re-poison + input restores.

typedef float f2v __attribute__((ext_vector_type(2)));
typedef float f4v __attribute__((ext_vector_type(4)));

#define B_ROWS 2048
#define K_DIM  512
#define O_DIM  512
#define NKQ    (K_DIM / 4)    // 128 k-quads
#define SPLITK 8
#define KQS    (NKQ / SPLITK) // 16 kq per split
#define RPW    8              // rows per wave
#define RPB    32             // rows per block (4 waves)
#define CPL    8              // cols per lane (col = j*64 + lane)
#define NOUT   (B_ROWS * O_DIM)

// Wt4[kq][o] = { W[o][4kq .. 4kq+3] }  (1 MB)
__global__ __launch_bounds__(256) void pack_w(
    const f4v* __restrict__ W4, f4v* __restrict__ Wt4)
{
    const int idx = blockIdx.x * 256 + threadIdx.x;  // 0..65535
    const int kq = idx & (NKQ - 1);
    const int o  = idx >> 7;
    Wt4[(size_t)kq * O_DIM + o] = W4[(size_t)o * NKQ + kq];
}

__global__ __launch_bounds__(256, 2) void tropical_main(
    const float* __restrict__ x, const f4v* __restrict__ Wt4,
    float* __restrict__ part)
{
    __shared__ f4v xs[RPB * KQS];   // 32 rows x 16 f4 = 8 KB

    const int t    = threadIdx.x;
    const int lane = t & 63;
    const int w    = t >> 6;             // wave 0..3 -> row group
    const int rb   = blockIdx.x * RPB;   // row block
    const int ks   = blockIdx.y;         // k split 0..7

    // stage this block's x strip (32 rows x 64 k) -> LDS; the only barrier
    {
        const f4v* xg = (const f4v*)x;
        const int r = t >> 3, q = t & 7;
        const size_t base = (size_t)(rb + r) * NKQ + ks * KQS;
        xs[r * KQS + q]     = xg[base + q];
        xs[r * KQS + q + 8] = xg[base + q + 8];
    }
    __syncthreads();

    const f4v* xw = xs + (w * RPW) * KQS;                       // wave's 8 rows
    const f4v* wp = Wt4 + (size_t)(ks * KQS) * O_DIM + lane;    // col base

    float acc[RPW][CPL];
#pragma unroll
    for (int r = 0; r < RPW; ++r)
#pragma unroll
        for (int j = 0; j < CPL; ++j) acc[r][j] = -INFINITY;

    f4v xr[2][RPW], wr[2][CPL];
    // preload kq = 0
#pragma unroll
    for (int r = 0; r < RPW; ++r) xr[0][r] = xw[r * KQS];
#pragma unroll
    for (int j = 0; j < CPL; ++j) wr[0][j] = wp[j * 64];

#pragma unroll 4
    for (int kq = 0; kq < KQS; ++kq) {
        const int cur = kq & 1, nxt = cur ^ 1;
        if (kq + 1 < KQS) {
            // prefetch kq+1 into the other buffer (in flight during compute)
#pragma unroll
            for (int j = 0; j < CPL; ++j)
                wr[nxt][j] = wp[(size_t)(kq + 1) * O_DIM + j * 64];
#pragma unroll
            for (int r = 0; r < RPW; ++r)
                xr[nxt][r] = xw[r * KQS + (kq + 1)];
        }
        // 256 VALU: per (r,j): 2x v_pk_add_f32 + 2x v_max3_f32 (4 k)
#pragma unroll
        for (int j = 0; j < CPL; ++j)
#pragma unroll
            for (int r = 0; r < RPW; ++r) {
                f2v s0 = xr[cur][r].xy + wr[cur][j].xy;
                acc[r][j] = fmaxf(acc[r][j], fmaxf(s0.x, s0.y));
                f2v s1 = xr[cur][r].zw + wr[cur][j].zw;
                acc[r][j] = fmaxf(acc[r][j], fmaxf(s1.x, s1.y));
            }
    }

    // partial store: coalesced dword per (row, j)
    float* pp = part + (size_t)ks * NOUT;
#pragma unroll
    for (int r = 0; r < RPW; ++r) {
        float* op = pp + (size_t)(rb + w * RPW + r) * O_DIM + lane;
#pragma unroll
        for (int j = 0; j < CPL; ++j) op[j * 64] = acc[r][j];
    }
}

__global__ __launch_bounds__(256) void tropical_reduce(
    const f4v* __restrict__ part, f4v* __restrict__ out)
{
    const int i = blockIdx.x * 256 + threadIdx.x;   // 0..262143
    const int Q = NOUT / 4;
    f4v r = part[i];
#pragma unroll
    for (int s = 1; s < SPLITK; ++s) {
        f4v v = part[i + (size_t)s * Q];
        r.x = fmaxf(r.x, v.x);
        r.y = fmaxf(r.y, v.y);
        r.z = fmaxf(r.z, v.z);
        r.w = fmaxf(r.w, v.w);
    }
    out[i] = r;
}

// Fallback (ws too small): correct direct kernel.
__global__ __launch_bounds__(256) void tropical_naive(
    const float* __restrict__ x, const float* __restrict__ W,
    float* __restrict__ out)
{
    const int o = blockIdx.x * 256 + threadIdx.x;
    const int col = o & (O_DIM - 1);
    const int row = o >> 9;
    const float* xr = x + (size_t)row * K_DIM;
    const float* wr = W + (size_t)col * K_DIM;
    float m = -INFINITY;
    for (int k = 0; k < K_DIM; ++k) m = fmaxf(m, xr[k] + wr[k]);
    out[o] = m;
}

extern "C" void kernel_launch(void* const* d_in, const int* in_sizes, int n_in,
                              void* d_out, int out_size, void* d_ws, size_t ws_size,
                              hipStream_t stream) {
    const float* x = (const float*)d_in[0];   // (2048, 512)
    const float* W = (const float*)d_in[1];   // (512, 512)
    float* out = (float*)d_out;               // (2048, 512)

    const size_t pack_bytes = (size_t)NKQ * O_DIM * sizeof(f4v);       // 1 MB
    const size_t part_off   = 4u << 20;                                // 4 MB align
    const size_t part_bytes = (size_t)SPLITK * NOUT * sizeof(float);   // 32 MB

    if (ws_size >= part_off + part_bytes && pack_bytes <= part_off) {
        f4v*   Wt4  = (f4v*)d_ws;
        float* part = (float*)((char*)d_ws + part_off);
        pack_w<<<(NKQ * O_DIM) / 256, 256, 0, stream>>>((const f4v*)W, Wt4);
        dim3 grid(B_ROWS / RPB, SPLITK);  // (64, 8) = 512 blocks
        tropical_main<<<grid, 256, 0, stream>>>(x, Wt4, part);
        tropical_reduce<<<(NOUT / 4) / 256, 256, 0, stream>>>(
            (const f4v*)part, (f4v*)out);
    } else {
        tropical_naive<<<NOUT / 256, 256, 0, stream>>>(x, W, out);
    }
}

// Round 7
// 93.011 us; speedup vs baseline: 1.4462x; 1.4462x over previous
//
#include <hip/hip_runtime.h>
#include <math.h>

// Tropical (max-plus) matmul: out[b,o] = max_k ( x[b,k] + W[o,k] )
// x: (2048,512) f32, W: (512,512) f32, out: (2048,512) f32.
//
// R6 post-mortem: explicit double-buffer arrays + runtime-guarded prefetch
// defeated SROA -> scratch spills (WRITE_SIZE 202 MB vs 36 justified, VGPR
// capped 128, main 75.5us). The R=8 x C=8 tiling's pipe math was right:
// per CU per kq: VALU 1024 cyc >= L1 1024 > LDS 768 -> VALU-bound at the
// 6.8us floor IF fed. R7 = same tiling, spill-proof implementation:
// straight-line SSA loads, no guards, #pragma unroll 8, barrier-free k-loop
// (compiler pipelines with its own vmcnt/lgkmcnt - m97 lesson).
// Fixed ~51us of dur_us is the harness ws re-poison + input restores.

typedef float f2v __attribute__((ext_vector_type(2)));
typedef float f4v __attribute__((ext_vector_type(4)));

#define B_ROWS 2048
#define K_DIM  512
#define O_DIM  512
#define NKQ    (K_DIM / 4)    // 128 k-quads (16 B)
#define SPLITK 8
#define KQS    (NKQ / SPLITK) // 16 kq per split
#define RPW    8              // rows per wave
#define RPB    32             // rows per block (4 waves)
#define CPL    8              // cols per lane (col = j*64 + lane)
#define NOUT   (B_ROWS * O_DIM)

// Wt4[kq][o] = { W[o][4kq .. 4kq+3] }  (1 MB)
__global__ __launch_bounds__(256) void pack_w(
    const f4v* __restrict__ W4, f4v* __restrict__ Wt4)
{
    const int idx = blockIdx.x * 256 + threadIdx.x;  // 0..65535
    const int kq = idx & (NKQ - 1);
    const int o  = idx >> 7;
    Wt4[(size_t)kq * O_DIM + o] = W4[(size_t)o * NKQ + kq];
}

__global__ __launch_bounds__(256, 2) void tropical_main(
    const float* __restrict__ x, const f4v* __restrict__ Wt4,
    float* __restrict__ part)
{
    __shared__ f4v xs[RPB * KQS];   // 32 rows x 16 f4v = 8 KB

    const int t    = threadIdx.x;
    const int lane = t & 63;
    const int w    = t >> 6;             // wave 0..3 -> row group
    const int rb   = blockIdx.x * RPB;   // row block
    const int ks   = blockIdx.y;         // k split 0..7

    // stage x strip (32 rows x 64 k) -> LDS; 2 coalesced f4v loads/thread
    {
        const f4v* xg = (const f4v*)x;   // 128 f4v per row
        const int r = t >> 4, q = t & 15;
        xs[t]       = xg[(size_t)(rb + r) * NKQ + ks * KQS + q];
        xs[t + 256] = xg[(size_t)(rb + r + 16) * NKQ + ks * KQS + q];
    }
    __syncthreads();   // the only barrier

    const f4v* xw = xs + (w * RPW) * KQS;                       // wave's 8 rows
    const f4v* wp = Wt4 + (size_t)(ks * KQS) * O_DIM + lane;    // col base

    float acc[RPW][CPL];
#pragma unroll
    for (int r = 0; r < RPW; ++r)
#pragma unroll
        for (int j = 0; j < CPL; ++j) acc[r][j] = -INFINITY;

    // Barrier-free k-loop: fresh SSA locals per iteration, no guards, no
    // persistent buffer arrays -> trivially SROA-able; compiler pipelines.
#pragma unroll 8
    for (int kq = 0; kq < KQS; ++kq) {
        f4v wv[CPL], xv[RPW];
#pragma unroll
        for (int j = 0; j < CPL; ++j)
            wv[j] = wp[(size_t)kq * O_DIM + j * 64];   // coalesced dwordx4
#pragma unroll
        for (int r = 0; r < RPW; ++r)
            xv[r] = xw[r * KQS + kq];                  // ds_read_b128 broadcast
#pragma unroll
        for (int j = 0; j < CPL; ++j)
#pragma unroll
            for (int r = 0; r < RPW; ++r) {
                f2v s0 = xv[r].xy + wv[j].xy;                    // v_pk_add_f32
                acc[r][j] = fmaxf(acc[r][j], fmaxf(s0.x, s0.y)); // v_max3_f32
                f2v s1 = xv[r].zw + wv[j].zw;
                acc[r][j] = fmaxf(acc[r][j], fmaxf(s1.x, s1.y));
            }
    }

    // partial store: coalesced dword per (row, j)
    float* pp = part + (size_t)ks * NOUT;
#pragma unroll
    for (int r = 0; r < RPW; ++r) {
        float* op = pp + (size_t)(rb + w * RPW + r) * O_DIM + lane;
#pragma unroll
        for (int j = 0; j < CPL; ++j) op[j * 64] = acc[r][j];
    }
}

__global__ __launch_bounds__(256) void tropical_reduce(
    const f4v* __restrict__ part, f4v* __restrict__ out)
{
    const int i = blockIdx.x * 256 + threadIdx.x;   // 0..262143
    const int Q = NOUT / 4;
    f4v r = part[i];
#pragma unroll
    for (int s = 1; s < SPLITK; ++s) {
        f4v v = part[i + (size_t)s * Q];
        r.x = fmaxf(r.x, v.x);
        r.y = fmaxf(r.y, v.y);
        r.z = fmaxf(r.z, v.z);
        r.w = fmaxf(r.w, v.w);
    }
    out[i] = r;
}

// Fallback (ws too small): correct direct kernel.
__global__ __launch_bounds__(256) void tropical_naive(
    const float* __restrict__ x, const float* __restrict__ W,
    float* __restrict__ out)
{
    const int o = blockIdx.x * 256 + threadIdx.x;
    const int col = o & (O_DIM - 1);
    const int row = o >> 9;
    const float* xr = x + (size_t)row * K_DIM;
    const float* wr = W + (size_t)col * K_DIM;
    float m = -INFINITY;
    for (int k = 0; k < K_DIM; ++k) m = fmaxf(m, xr[k] + wr[k]);
    out[o] = m;
}

extern "C" void kernel_launch(void* const* d_in, const int* in_sizes, int n_in,
                              void* d_out, int out_size, void* d_ws, size_t ws_size,
                              hipStream_t stream) {
    const float* x = (const float*)d_in[0];   // (2048, 512)
    const float* W = (const float*)d_in[1];   // (512, 512)
    float* out = (float*)d_out;               // (2048, 512)

    const size_t pack_bytes = (size_t)NKQ * O_DIM * sizeof(f4v);       // 1 MB
    const size_t part_off   = 4u << 20;                                // 4 MB
    const size_t part_bytes = (size_t)SPLITK * NOUT * sizeof(float);   // 32 MB

    if (ws_size >= part_off + part_bytes && pack_bytes <= part_off) {
        f4v*   Wt4  = (f4v*)d_ws;
        float* part = (float*)((char*)d_ws + part_off);
        pack_w<<<(NKQ * O_DIM) / 256, 256, 0, stream>>>((const f4v*)W, Wt4);
        dim3 grid(B_ROWS / RPB, SPLITK);  // (64, 8) = 512 blocks
        tropical_main<<<grid, 256, 0, stream>>>(x, Wt4, part);
        tropical_reduce<<<(NOUT / 4) / 256, 256, 0, stream>>>(
            (const f4v*)part, (f4v*)out);
    } else {
        tropical_naive<<<NOUT / 256, 256, 0, stream>>>(x, W, out);
    }
}